// Round 1
// baseline (109.789 us; speedup 1.0000x reference)
//
#include <hip/hip_runtime.h>

// Problem constants (fixed by the reference setup)
#define NN   32
#define CCH  2
#define PP   (512*512)     // 262144 pixels per (n,c) row
#define RR   (NN*CCH)      // 64 rows
#define NB   2048          // distance-quantization buckets over [0,1]
#define BPR  8             // histogram blocks per row
#define CHUNK (PP/BPR)     // 32768 elements per hist block
#define HT   512           // threads in hist kernel
#define ST   256           // threads in scan kernel

static_assert(NB % HT == 0 || HT % NB == 0, "");
static_assert(NB % ST == 0, "");
static_assert(CHUNK % (HT*4) == 0, "");

__device__ __forceinline__ double iou_f(double msum, unsigned k, unsigned cs) {
    if (k == 0u) return 0.0;              // iou "before position 1" is defined as 0
    if (msum == 0.0) return 1.0;          // no ones: inter=0, union=k -> iou=1
    const double dk = (double)k, dcs = (double)cs;
    return 1.0 - (msum - dcs) / (msum + dk - dcs);
}

// Kernel 1: per-(row, chunk) privatized LDS histograms of quantized distance.
// Outputs per-block partial histograms (no global atomics -> deterministic).
__global__ __launch_bounds__(HT) void hist_kernel(
        const float* __restrict__ x, const int* __restrict__ tgt,
        unsigned* __restrict__ g_cnt, unsigned* __restrict__ g_ones,
        float* __restrict__ g_dsum, unsigned* __restrict__ g_pos)
{
    __shared__ unsigned s_cnt[NB];
    __shared__ unsigned s_ones[NB];
    __shared__ float    s_dsum[NB];
    __shared__ unsigned s_pos[HT/64];

    const int r = blockIdx.x / BPR, b = blockIdx.x % BPR;
    const int n = r / CCH, c = r % CCH;
    const int tid = threadIdx.x;

    for (int i = tid; i < NB; i += HT) { s_cnt[i] = 0u; s_ones[i] = 0u; s_dsum[i] = 0.f; }
    __syncthreads();

    const float* xrow = x   + (size_t)r * PP;   // inputs laid out [N][C][P] -> row r
    const int*   trow = tgt + (size_t)n * PP;   // targets [N][P]
    const int start = b * CHUNK;

    unsigned pos = 0;
    for (int it = 0; it < CHUNK/(HT*4); ++it) {
        const int p = start + it*(HT*4) + tid*4;
        const float4 xv = *reinterpret_cast<const float4*>(xrow + p);
        const int4   tv = *reinterpret_cast<const int4*>(trow + p);
        #pragma unroll
        for (int j = 0; j < 4; ++j) {
            const float xs = (j==0) ? xv.x : (j==1) ? xv.y : (j==2) ? xv.z : xv.w;
            const int   ts = (j==0) ? tv.x : (j==1) ? tv.y : (j==2) ? tv.z : tv.w;
            const int   m  = (ts == c);
            const float d  = m ? (1.0f - xs) : xs;      // |mask - x|, exact
            int bk = (int)(d * (float)NB);              // monotone quantizer
            bk = bk > NB-1 ? NB-1 : bk;
            atomicAdd(&s_cnt[bk], 1u);
            if (m) atomicAdd(&s_ones[bk], 1u);
            atomicAdd(&s_dsum[bk], d);
            pos += (xs > 0.25f) ? 1u : 0u;
        }
    }

    // reduce pos across the block (wave shuffle, then tiny LDS)
    for (int off = 32; off; off >>= 1) pos += __shfl_down(pos, off);
    if ((tid & 63) == 0) s_pos[tid >> 6] = pos;
    __syncthreads();   // also guarantees all LDS histogram atomics are complete
    if (tid == 0) {
        unsigned t = 0;
        #pragma unroll
        for (int w = 0; w < HT/64; ++w) t += s_pos[w];
        g_pos[blockIdx.x] = t;
    }

    const size_t base = (size_t)blockIdx.x * NB;   // blockIdx.x == r*BPR + b
    for (int i = tid; i < NB; i += HT) {
        g_cnt[base+i]  = s_cnt[i];
        g_ones[base+i] = s_ones[i];
        g_dsum[base+i] = s_dsum[i];
    }
}

// Kernel 2: per-row — merge partials, suffix-scan buckets in descending-d
// order, accumulate sum( d_bar * (iou_incl - iou_excl) ) in double.
__global__ __launch_bounds__(ST) void scan_kernel(
        const unsigned* __restrict__ g_cnt, const unsigned* __restrict__ g_ones,
        const float* __restrict__ g_dsum, const unsigned* __restrict__ g_pos,
        float* __restrict__ g_row, float* __restrict__ g_valid)
{
    __shared__ unsigned m_cnt[NB];
    __shared__ unsigned m_ones[NB];
    __shared__ float    m_dsum[NB];
    __shared__ unsigned long long s_scan[ST];
    __shared__ double   s_red[ST/64];

    const int r = blockIdx.x;
    const int tid = threadIdx.x;

    // merge the BPR partial histograms (fixed order -> deterministic)
    for (int i = tid; i < NB; i += ST) {
        unsigned cs = 0, os = 0; float ds = 0.f;
        #pragma unroll
        for (int b = 0; b < BPR; ++b) {
            const size_t idx = ((size_t)(r*BPR + b))*NB + i;
            cs += g_cnt[idx]; os += g_ones[idx]; ds += g_dsum[idx];
        }
        m_cnt[i] = cs; m_ones[i] = os; m_dsum[i] = ds;
    }
    __syncthreads();

    constexpr int Q = NB/ST;   // 8 buckets per thread, contiguous in scan order
    unsigned lc = 0, lo = 0;
    #pragma unroll
    for (int q = 0; q < Q; ++q) {
        const int bk = NB-1 - (tid*Q + q);   // descending distance
        lc += m_cnt[bk]; lo += m_ones[bk];
    }

    // packed (cnt<<32 | ones) inclusive Hillis-Steele block scan
    const unsigned long long v = ((unsigned long long)lc << 32) | (unsigned long long)lo;
    s_scan[tid] = v;
    __syncthreads();
    for (int off = 1; off < ST; off <<= 1) {
        const unsigned long long add = (tid >= off) ? s_scan[tid-off] : 0ULL;
        __syncthreads();
        s_scan[tid] += add;
        __syncthreads();
    }
    const unsigned long long excl = s_scan[tid] - v;
    const unsigned long long tot  = s_scan[ST-1];
    const unsigned msum = (unsigned)(tot & 0xffffffffULL);

    unsigned k  = (unsigned)(excl >> 32);
    unsigned cs = (unsigned)(excl & 0xffffffffULL);
    const double dmsum = (double)msum;

    double acc = 0.0;
    #pragma unroll
    for (int q = 0; q < Q; ++q) {
        const int bk = NB-1 - (tid*Q + q);
        const unsigned c_ = m_cnt[bk];
        if (c_) {
            const double ip = iou_f(dmsum, k, cs);
            k += c_; cs += m_ones[bk];
            const double in_ = iou_f(dmsum, k, cs);
            acc += ((double)m_dsum[bk] / (double)c_) * (in_ - ip);
        }
    }

    for (int off = 32; off; off >>= 1) acc += __shfl_down(acc, off);
    if ((tid & 63) == 0) s_red[tid >> 6] = acc;
    __syncthreads();
    if (tid == 0) {
        double t = 0.0;
        #pragma unroll
        for (int w = 0; w < ST/64; ++w) t += s_red[w];
        unsigned pos = 0;
        for (int b = 0; b < BPR; ++b) pos += g_pos[r*BPR + b];
        const bool valid = !(msum == 0u && pos == 0u);
        const double W[CCH] = {1.428, 40.097};
        g_row[r]   = valid ? (float)(t * W[r % CCH]) : 0.f;
        g_valid[r] = valid ? 1.f : 0.f;
    }
}

// Kernel 3: one wave reduces the 64 rows to the final scalar.
__global__ __launch_bounds__(64) void final_kernel(
        const float* __restrict__ g_row, const float* __restrict__ g_valid,
        float* __restrict__ out)
{
    const int tid = threadIdx.x;
    double t = (double)g_row[tid];
    double v = (double)g_valid[tid];
    for (int off = 32; off; off >>= 1) { t += __shfl_down(t, off); v += __shfl_down(v, off); }
    if (tid == 0) out[0] = (float)(t / (double)NN / v);
}

extern "C" void kernel_launch(void* const* d_in, const int* in_sizes, int n_in,
                              void* d_out, int out_size, void* d_ws, size_t ws_size,
                              hipStream_t stream) {
    const float* x   = (const float*)d_in[0];
    const int*   tgt = (const int*)d_in[1];
    float* out = (float*)d_out;

    // workspace layout (~12.6 MB, every byte written before read -> no memset)
    const size_t SZH = (size_t)RR * BPR * NB;
    unsigned* g_cnt  = (unsigned*)d_ws;
    unsigned* g_ones = g_cnt + SZH;
    float*    g_dsum = (float*)(g_ones + SZH);
    unsigned* g_pos  = (unsigned*)(g_dsum + SZH);
    float*    g_row  = (float*)(g_pos + RR*BPR);
    float*    g_valid = g_row + RR;

    hist_kernel<<<RR*BPR, HT, 0, stream>>>(x, tgt, g_cnt, g_ones, g_dsum, g_pos);
    scan_kernel<<<RR, ST, 0, stream>>>(g_cnt, g_ones, g_dsum, g_pos, g_row, g_valid);
    final_kernel<<<1, 64, 0, stream>>>(g_row, g_valid, out);
}

// Round 2
// 32.364 us; speedup vs baseline: 3.3923x; 3.3923x over previous
//
#include <hip/hip_runtime.h>

// Problem constants (fixed by the reference setup)
#define NN   32
#define CCH  2
#define PP   (512*512)     // 262144 pixels per (n,c) row
#define RR   (NN*CCH)      // 64 rows
#define NB   2048          // distance-quantization buckets over [0,1]
#define BPR  16            // histogram blocks per row
#define CHUNK (PP/BPR)     // 16384 elements per hist block
#define HT   512           // threads in hist kernel
#define ST   256           // threads in scan kernel

static_assert(CHUNK % (HT*4) == 0, "");
static_assert(NB % ST == 0, "");
static_assert(CHUNK < 65536, "packed 16-bit cnt would overflow");

__device__ __forceinline__ double iou_f(double msum, unsigned k, unsigned cs) {
    if (k == 0u) return 0.0;              // iou "before position 1" is 0
    if (msum == 0.0) return 1.0;          // no ones: inter=0, union=k -> iou=1
    const double dk = (double)k, dcs = (double)cs;
    return 1.0 - (msum - dcs) / (msum + dk - dcs);
}

// Kernel 1: per-(row, chunk) privatized LDS histogram of quantized distance.
// Single packed u32 per bucket: (cnt << 16) | ones. One LDS atomic per pixel.
// Pure-integer -> bit-deterministic. Partials out per block (no global atomics).
__global__ __launch_bounds__(HT) void hist_kernel(
        const float* __restrict__ x, const int* __restrict__ tgt,
        unsigned* __restrict__ g_hist, unsigned* __restrict__ g_pos)
{
    __shared__ unsigned s_hist[NB];          // 8 KB -> 4 blocks/CU, 32 waves/CU
    __shared__ unsigned s_pos[HT/64];

    const int r = blockIdx.x / BPR, b = blockIdx.x % BPR;
    const int n = r / CCH, c = r % CCH;
    const int tid = threadIdx.x;

    for (int i = tid; i < NB; i += HT) s_hist[i] = 0u;
    __syncthreads();

    const float* xrow = x   + (size_t)r * PP;   // inputs [N][C][P] -> row r
    const int*   trow = tgt + (size_t)n * PP;   // targets [N][P]
    const int start = b * CHUNK;

    unsigned pos = 0;
    #pragma unroll
    for (int it = 0; it < CHUNK/(HT*4); ++it) {
        const int p = start + it*(HT*4) + tid*4;
        const float4 xv = *reinterpret_cast<const float4*>(xrow + p);
        const int4   tv = *reinterpret_cast<const int4*>(trow + p);
        #pragma unroll
        for (int j = 0; j < 4; ++j) {
            const float xs = (j==0) ? xv.x : (j==1) ? xv.y : (j==2) ? xv.z : xv.w;
            const int   ts = (j==0) ? tv.x : (j==1) ? tv.y : (j==2) ? tv.z : tv.w;
            const unsigned m = (ts == c) ? 1u : 0u;
            const float d  = m ? (1.0f - xs) : xs;      // |mask - x|, exact
            int bk = (int)(d * (float)NB);              // monotone quantizer
            bk = bk > NB-1 ? NB-1 : bk;
            atomicAdd(&s_hist[bk], 0x10000u | m);
            pos += (xs > 0.25f) ? 1u : 0u;
        }
    }

    // reduce pos across the block (wave shuffle, then tiny LDS)
    for (int off = 32; off; off >>= 1) pos += __shfl_down(pos, off);
    if ((tid & 63) == 0) s_pos[tid >> 6] = pos;
    __syncthreads();   // also guarantees all LDS histogram atomics complete
    if (tid == 0) {
        unsigned t = 0;
        #pragma unroll
        for (int w = 0; w < HT/64; ++w) t += s_pos[w];
        g_pos[blockIdx.x] = t;
    }

    const size_t base = (size_t)blockIdx.x * NB;   // blockIdx.x == r*BPR + b
    for (int i = tid; i < NB; i += HT) g_hist[base+i] = s_hist[i];
}

// Kernel 2: per-row — merge partials, suffix-scan buckets in descending-d
// order, accumulate sum( d_mid * (iou_incl - iou_excl) ) in double.
__global__ __launch_bounds__(ST) void scan_kernel(
        const unsigned* __restrict__ g_hist, const unsigned* __restrict__ g_pos,
        float* __restrict__ g_row, float* __restrict__ g_valid)
{
    __shared__ unsigned m_cnt[NB];
    __shared__ unsigned m_ones[NB];
    __shared__ unsigned long long s_scan[ST];
    __shared__ double   s_red[ST/64];

    const int r = blockIdx.x;
    const int tid = threadIdx.x;

    // merge the BPR partial histograms (fixed order -> deterministic)
    for (int i = tid; i < NB; i += ST) {
        unsigned cs = 0, os = 0;
        #pragma unroll
        for (int b = 0; b < BPR; ++b) {
            const unsigned v = g_hist[((size_t)(r*BPR + b))*NB + i];
            cs += v >> 16; os += v & 0xffffu;
        }
        m_cnt[i] = cs; m_ones[i] = os;
    }
    __syncthreads();

    constexpr int Q = NB/ST;   // 8 buckets per thread, contiguous in scan order
    unsigned lc = 0, lo = 0;
    #pragma unroll
    for (int q = 0; q < Q; ++q) {
        const int bk = NB-1 - (tid*Q + q);   // descending distance
        lc += m_cnt[bk]; lo += m_ones[bk];
    }

    // packed (cnt<<32 | ones) inclusive Hillis-Steele block scan
    const unsigned long long v = ((unsigned long long)lc << 32) | (unsigned long long)lo;
    s_scan[tid] = v;
    __syncthreads();
    for (int off = 1; off < ST; off <<= 1) {
        const unsigned long long add = (tid >= off) ? s_scan[tid-off] : 0ULL;
        __syncthreads();
        s_scan[tid] += add;
        __syncthreads();
    }
    const unsigned long long excl = s_scan[tid] - v;
    const unsigned long long tot  = s_scan[ST-1];
    const unsigned msum = (unsigned)(tot & 0xffffffffULL);

    unsigned k  = (unsigned)(excl >> 32);
    unsigned cs = (unsigned)(excl & 0xffffffffULL);
    const double dmsum = (double)msum;

    double acc = 0.0;
    #pragma unroll
    for (int q = 0; q < Q; ++q) {
        const int bk = NB-1 - (tid*Q + q);
        const unsigned c_ = m_cnt[bk];
        if (c_) {
            const double ip = iou_f(dmsum, k, cs);
            k += c_; cs += m_ones[bk];
            const double in_ = iou_f(dmsum, k, cs);
            const double dmid = ((double)bk + 0.5) * (1.0 / (double)NB);
            acc += dmid * (in_ - ip);
        }
    }

    for (int off = 32; off; off >>= 1) acc += __shfl_down(acc, off);
    if ((tid & 63) == 0) s_red[tid >> 6] = acc;
    __syncthreads();
    if (tid == 0) {
        double t = 0.0;
        #pragma unroll
        for (int w = 0; w < ST/64; ++w) t += s_red[w];
        unsigned pos = 0;
        for (int b = 0; b < BPR; ++b) pos += g_pos[r*BPR + b];
        const bool valid = !(msum == 0u && pos == 0u);
        const double W[CCH] = {1.428, 40.097};
        g_row[r]   = valid ? (float)(t * W[r % CCH]) : 0.f;
        g_valid[r] = valid ? 1.f : 0.f;
    }
}

// Kernel 3: one wave reduces the 64 rows to the final scalar.
__global__ __launch_bounds__(64) void final_kernel(
        const float* __restrict__ g_row, const float* __restrict__ g_valid,
        float* __restrict__ out)
{
    const int tid = threadIdx.x;
    double t = (double)g_row[tid];
    double v = (double)g_valid[tid];
    for (int off = 32; off; off >>= 1) { t += __shfl_down(t, off); v += __shfl_down(v, off); }
    if (tid == 0) out[0] = (float)(t / (double)NN / v);
}

extern "C" void kernel_launch(void* const* d_in, const int* in_sizes, int n_in,
                              void* d_out, int out_size, void* d_ws, size_t ws_size,
                              hipStream_t stream) {
    const float* x   = (const float*)d_in[0];
    const int*   tgt = (const int*)d_in[1];
    float* out = (float*)d_out;

    // workspace layout (~8 MB, every byte written before read -> no memset)
    const size_t SZH = (size_t)RR * BPR * NB;
    unsigned* g_hist = (unsigned*)d_ws;
    unsigned* g_pos  = g_hist + SZH;
    float*    g_row  = (float*)(g_pos + RR*BPR);
    float*    g_valid = g_row + RR;

    hist_kernel<<<RR*BPR, HT, 0, stream>>>(x, tgt, g_hist, g_pos);
    scan_kernel<<<RR, ST, 0, stream>>>(g_hist, g_pos, g_row, g_valid);
    final_kernel<<<1, 64, 0, stream>>>(g_row, g_valid, out);
}

// Round 3
// 30.513 us; speedup vs baseline: 3.5981x; 1.0607x over previous
//
#include <hip/hip_runtime.h>

// Problem constants (fixed by the reference setup)
#define NN   32
#define CCH  2
#define PP   (512*512)     // 262144 pixels per (n,c) row
#define RR   (NN*CCH)      // 64 rows
#define NB   1024          // distance-quantization buckets over [0,1]
#define BPR  16            // histogram blocks per row
#define CHUNK (PP/BPR)     // 16384 elements per hist block
#define HT   512           // threads in hist kernel
#define ST   256           // threads in scan kernel

static_assert(CHUNK % (HT*8) == 0, "");
static_assert(NB % ST == 0, "");
static_assert(CHUNK < 65536, "packed 16-bit cnt would overflow");
static_assert(RR <= 64, "final reduce assumes one wave");

__device__ __forceinline__ double iou_f(double msum, unsigned k, unsigned cs) {
    if (k == 0u) return 0.0;              // iou "before position 1" is 0
    if (msum == 0.0) return 1.0;          // no ones: inter=0, union=k -> iou=1
    const double dk = (double)k, dcs = (double)cs;
    return 1.0 - (msum - dcs) / (msum + dk - dcs);
}

// Kernel 1: per-(row, chunk) privatized LDS histogram of quantized distance.
// Single packed u32 per bucket: (cnt << 16) | ones. One LDS atomic per pixel.
// Pure-integer -> bit-deterministic. Partials out per block (no global atomics).
__global__ __launch_bounds__(HT) void hist_kernel(
        const float* __restrict__ x, const int* __restrict__ tgt,
        unsigned* __restrict__ g_hist, unsigned* __restrict__ g_pos,
        unsigned* __restrict__ g_ticket)
{
    __shared__ unsigned s_hist[NB];          // 4 KB
    __shared__ unsigned s_pos[HT/64];

    const int r = blockIdx.x / BPR, b = blockIdx.x % BPR;
    const int n = r / CCH, c = r % CCH;
    const int tid = threadIdx.x;

    if (blockIdx.x == 0 && tid == 0) *g_ticket = 0u;   // reset scan's ticket

    for (int i = tid; i < NB; i += HT) s_hist[i] = 0u;
    __syncthreads();

    const float* xrow = x   + (size_t)r * PP;   // inputs [N][C][P] -> row r
    const int*   trow = tgt + (size_t)n * PP;   // targets [N][P]
    const int start = b * CHUNK;

    unsigned pos = 0;
    #pragma unroll
    for (int it = 0; it < CHUNK/(HT*8); ++it) {
        const int p = start + it*(HT*8) + tid*8;
        const float4 xv0 = *reinterpret_cast<const float4*>(xrow + p);
        const float4 xv1 = *reinterpret_cast<const float4*>(xrow + p + 4);
        const int4   tv0 = *reinterpret_cast<const int4*>(trow + p);
        const int4   tv1 = *reinterpret_cast<const int4*>(trow + p + 4);
        const float xs[8] = {xv0.x,xv0.y,xv0.z,xv0.w, xv1.x,xv1.y,xv1.z,xv1.w};
        const int   ts[8] = {tv0.x,tv0.y,tv0.z,tv0.w, tv1.x,tv1.y,tv1.z,tv1.w};
        #pragma unroll
        for (int j = 0; j < 8; ++j) {
            const unsigned m = (ts[j] == c) ? 1u : 0u;
            const float d  = m ? (1.0f - xs[j]) : xs[j];   // |mask - x|, exact
            int bk = (int)(d * (float)NB);                 // monotone quantizer
            bk = bk > NB-1 ? NB-1 : bk;
            atomicAdd(&s_hist[bk], 0x10000u | m);
            pos += (xs[j] > 0.25f) ? 1u : 0u;
        }
    }

    // reduce pos across the block (wave shuffle, then tiny LDS)
    for (int off = 32; off; off >>= 1) pos += __shfl_down(pos, off);
    if ((tid & 63) == 0) s_pos[tid >> 6] = pos;
    __syncthreads();   // also guarantees all LDS histogram atomics complete
    if (tid == 0) {
        unsigned t = 0;
        #pragma unroll
        for (int w = 0; w < HT/64; ++w) t += s_pos[w];
        g_pos[blockIdx.x] = t;
    }

    const size_t base = (size_t)blockIdx.x * NB;   // blockIdx.x == r*BPR + b
    for (int i = tid; i < NB; i += HT) g_hist[base+i] = s_hist[i];
}

// Kernel 2: per-row — merge partials, suffix-scan buckets in descending-d
// order, accumulate sum( d_mid * (iou_incl - iou_excl) ) in double.
// The last block to finish (device ticket) reduces the 64 rows to the scalar.
__global__ __launch_bounds__(ST) void scan_kernel(
        const unsigned* __restrict__ g_hist, const unsigned* __restrict__ g_pos,
        float* __restrict__ g_row, float* __restrict__ g_valid,
        unsigned* __restrict__ g_ticket, float* __restrict__ out)
{
    __shared__ unsigned m_cnt[NB];
    __shared__ unsigned m_ones[NB];
    __shared__ unsigned long long s_scan[ST];
    __shared__ double   s_red[ST/64];
    __shared__ unsigned s_ticket;

    const int r = blockIdx.x;
    const int tid = threadIdx.x;

    // merge the BPR partial histograms (fixed order -> deterministic)
    for (int i = tid; i < NB; i += ST) {
        unsigned cs = 0, os = 0;
        #pragma unroll
        for (int b = 0; b < BPR; ++b) {
            const unsigned v = g_hist[((size_t)(r*BPR + b))*NB + i];
            cs += v >> 16; os += v & 0xffffu;
        }
        m_cnt[i] = cs; m_ones[i] = os;
    }
    __syncthreads();

    constexpr int Q = NB/ST;   // buckets per thread, contiguous in scan order
    unsigned lc = 0, lo = 0;
    #pragma unroll
    for (int q = 0; q < Q; ++q) {
        const int bk = NB-1 - (tid*Q + q);   // descending distance
        lc += m_cnt[bk]; lo += m_ones[bk];
    }

    // packed (cnt<<32 | ones) inclusive Hillis-Steele block scan
    const unsigned long long v = ((unsigned long long)lc << 32) | (unsigned long long)lo;
    s_scan[tid] = v;
    __syncthreads();
    for (int off = 1; off < ST; off <<= 1) {
        const unsigned long long add = (tid >= off) ? s_scan[tid-off] : 0ULL;
        __syncthreads();
        s_scan[tid] += add;
        __syncthreads();
    }
    const unsigned long long excl = s_scan[tid] - v;
    const unsigned long long tot  = s_scan[ST-1];
    const unsigned msum = (unsigned)(tot & 0xffffffffULL);

    unsigned k  = (unsigned)(excl >> 32);
    unsigned cs = (unsigned)(excl & 0xffffffffULL);
    const double dmsum = (double)msum;

    double acc = 0.0;
    #pragma unroll
    for (int q = 0; q < Q; ++q) {
        const int bk = NB-1 - (tid*Q + q);
        const unsigned c_ = m_cnt[bk];
        if (c_) {
            const double ip = iou_f(dmsum, k, cs);
            k += c_; cs += m_ones[bk];
            const double in_ = iou_f(dmsum, k, cs);
            const double dmid = ((double)bk + 0.5) * (1.0 / (double)NB);
            acc += dmid * (in_ - ip);
        }
    }

    for (int off = 32; off; off >>= 1) acc += __shfl_down(acc, off);
    if ((tid & 63) == 0) s_red[tid >> 6] = acc;
    __syncthreads();
    if (tid == 0) {
        double t = 0.0;
        #pragma unroll
        for (int w = 0; w < ST/64; ++w) t += s_red[w];
        unsigned pos = 0;
        for (int b = 0; b < BPR; ++b) pos += g_pos[r*BPR + b];
        const bool valid = !(msum == 0u && pos == 0u);
        const double W[CCH] = {1.428, 40.097};
        g_row[r]   = valid ? (float)(t * W[r % CCH]) : 0.f;
        g_valid[r] = valid ? 1.f : 0.f;
        __threadfence();                       // publish row result device-wide
        s_ticket = atomicAdd(g_ticket, 1u);    // device-scope by default
    }
    __syncthreads();

    if (s_ticket == RR - 1) {                  // last block reduces all rows
        __threadfence();
        if (tid < 64) {
            const volatile float* vr = g_row;
            const volatile float* vv = g_valid;
            double t = (tid < RR) ? (double)vr[tid] : 0.0;
            double vl = (tid < RR) ? (double)vv[tid] : 0.0;
            for (int off = 32; off; off >>= 1) {
                t  += __shfl_down(t, off);
                vl += __shfl_down(vl, off);
            }
            if (tid == 0) out[0] = (float)(t / (double)NN / vl);
        }
    }
}

extern "C" void kernel_launch(void* const* d_in, const int* in_sizes, int n_in,
                              void* d_out, int out_size, void* d_ws, size_t ws_size,
                              hipStream_t stream) {
    const float* x   = (const float*)d_in[0];
    const int*   tgt = (const int*)d_in[1];
    float* out = (float*)d_out;

    // workspace layout (~4.2 MB, every word written before read -> no memset)
    const size_t SZH = (size_t)RR * BPR * NB;
    unsigned* g_hist  = (unsigned*)d_ws;
    unsigned* g_pos   = g_hist + SZH;
    float*    g_row   = (float*)(g_pos + RR*BPR);
    float*    g_valid = g_row + RR;
    unsigned* g_ticket = (unsigned*)(g_valid + RR);

    hist_kernel<<<RR*BPR, HT, 0, stream>>>(x, tgt, g_hist, g_pos, g_ticket);
    scan_kernel<<<RR, ST, 0, stream>>>(g_hist, g_pos, g_row, g_valid, g_ticket, out);
}